// Round 1
// baseline (169.469 us; speedup 1.0000x reference)
//
#include <hip/hip_runtime.h>
#include <stdint.h>

#define DEV __device__ __forceinline__

typedef __attribute__((ext_vector_type(4))) float f32x4;
typedef __attribute__((ext_vector_type(8))) short s16x8;
typedef __attribute__((ext_vector_type(8))) __bf16 bf16x8;

constexpr int kB = 16, kC = 512, kN = 1024;
constexpr int kO = 1536;
constexpr int kG = 32, kCPG = 16;
constexpr float kEps = 1e-5f;

DEV unsigned short f2bf(float f) {
  union { float f; uint32_t u; } cv; cv.f = f;
  uint32_t u = cv.u;
  return (unsigned short)((u + 0x7FFFu + ((u >> 16) & 1u)) >> 16);
}

DEV bf16x8 asbf(s16x8 v) { return __builtin_bit_cast(bf16x8, v); }

DEV void gl_lds16(const void* g, void* l) {
  __builtin_amdgcn_global_load_lds(
      (const __attribute__((address_space(1))) uint32_t*)g,
      (__attribute__((address_space(3))) uint32_t*)l, 16, 0, 0);
}

// ---------------- weight fp32 -> bf16 ----------------
__global__ __launch_bounds__(256) void k_wconv(const float* __restrict__ src,
                                               unsigned short* __restrict__ dst, int n4) {
  int i = blockIdx.x * 256 + threadIdx.x;
  if (i >= n4) return;
  f32x4 v = ((const f32x4*)src)[i];
  unsigned short o[4];
  o[0] = f2bf(v[0]); o[1] = f2bf(v[1]); o[2] = f2bf(v[2]); o[3] = f2bf(v[3]);
  ((uint2*)dst)[i] = *(uint2*)o;
}

// ---------------- GroupNorm stats: one block per (b,g) ----------------
__global__ __launch_bounds__(256) void k_gnstats(const float* __restrict__ x,
                                                 float* __restrict__ meanp,
                                                 float* __restrict__ rstdp) {
  int bg = blockIdx.x;  // 0..511
  const f32x4* p4 = (const f32x4*)(x + (size_t)bg * (kCPG * kN));
  float s = 0.f, s2 = 0.f;
  for (int i = threadIdx.x; i < (kCPG * kN / 4); i += 256) {
    f32x4 v = p4[i];
    s += v[0] + v[1] + v[2] + v[3];
    s2 += v[0] * v[0] + v[1] * v[1] + v[2] * v[2] + v[3] * v[3];
  }
#pragma unroll
  for (int m = 32; m >= 1; m >>= 1) { s += __shfl_xor(s, m); s2 += __shfl_xor(s2, m); }
  __shared__ float rb[8];
  int lane = threadIdx.x & 63, wid = threadIdx.x >> 6;
  if (lane == 0) { rb[wid * 2] = s; rb[wid * 2 + 1] = s2; }
  __syncthreads();
  if (threadIdx.x == 0) {
    float S = rb[0] + rb[2] + rb[4] + rb[6];
    float S2 = rb[1] + rb[3] + rb[5] + rb[7];
    float mu = S * (1.f / 16384.f);
    float var = S2 * (1.f / 16384.f) - mu * mu;
    meanp[bg] = mu;
    rstdp[bg] = rsqrtf(var + kEps);
  }
}

// ---------------- GN apply + transpose to token-major bf16 ----------------
__global__ __launch_bounds__(256) void k_gnapply(const float* __restrict__ x,
                                                 const float* __restrict__ gw,
                                                 const float* __restrict__ gb,
                                                 const float* __restrict__ meanp,
                                                 const float* __restrict__ rstdp,
                                                 unsigned short* __restrict__ xt) {
  int bid = blockIdx.x;
  int b = bid >> 7;
  int ct = (bid >> 4) & 7;
  int nt = bid & 15;
  int c0 = ct * 64, n0 = nt * 64;
  __shared__ float tile[64][65];
  int t = threadIdx.x;
#pragma unroll
  for (int pass = 0; pass < 4; ++pass) {
    int r = pass * 16 + (t >> 4);
    int col = (t & 15) << 2;
    int c = c0 + r;
    f32x4 v = *(const f32x4*)(x + ((size_t)b * kC + c) * kN + n0 + col);
    int g = b * kG + (c >> 4);
    float rs = rstdp[g];
    float a = rs * gw[c];
    float bb = gb[c] - meanp[g] * a;
    tile[r][col + 0] = v[0] * a + bb;
    tile[r][col + 1] = v[1] * a + bb;
    tile[r][col + 2] = v[2] * a + bb;
    tile[r][col + 3] = v[3] * a + bb;
  }
  __syncthreads();
#pragma unroll
  for (int pass = 0; pass < 2; ++pass) {
    int nr = pass * 32 + (t >> 3);
    int cb = (t & 7) << 3;
    unsigned short o[8];
#pragma unroll
    for (int j = 0; j < 8; ++j) o[j] = f2bf(tile[cb + j][nr]);
    *(uint4*)(xt + ((size_t)b * kN + n0 + nr) * kC + c0 + cb) = *(uint4*)o;
  }
}

// ---------------- GEMM: D[n][o] = sum_c act[b][n][c] * W[o][c]  ----------------
// MODE 0: qkv -> qkT (o<1024, bf16 token-major) + vbuf (o>=1024, d-major packed)
// MODE 1: proj -> out fp32 (b,c,n) with bias + residual
template <int MODE>
__global__ __launch_bounds__(256) void k_gemm(const unsigned short* __restrict__ act,
                                              const unsigned short* __restrict__ wb,
                                              const float* __restrict__ bias,
                                              unsigned short* __restrict__ qkT,
                                              unsigned short* __restrict__ vbuf,
                                              const float* __restrict__ xres,
                                              float* __restrict__ outp) {
  int b = blockIdx.y;
  int nt = blockIdx.x & 7, ot = blockIdx.x >> 3;
  int n0 = nt << 7, o0 = ot << 7;
  int t = threadIdx.x, lane = t & 63, wid = t >> 6;
  int wr = wid >> 1, wc = wid & 1;
  __shared__ unsigned short sA[128 * 64];
  __shared__ unsigned short sB[128 * 64];
  f32x4 acc[4][4];
  const f32x4 zf = {0.f, 0.f, 0.f, 0.f};
#pragma unroll
  for (int i = 0; i < 4; ++i)
#pragma unroll
    for (int j = 0; j < 4; ++j) acc[i][j] = zf;
  const size_t rowb = (size_t)b * kN;
#pragma unroll 1
  for (int kt = 0; kt < 8; ++kt) {
    const int k0 = kt << 6;
    __syncthreads();
#pragma unroll
    for (int p = 0; p < 4; ++p) {
      const int id = p * 256 + t;
      const int row = id >> 3, cp = id & 7;
      const int cl = cp ^ (row & 7);  // source chunk pre-swizzle (involution)
      gl_lds16(act + (rowb + n0 + row) * (size_t)kC + k0 + cl * 8,
               (char*)sA + (p * 256 + wid * 64) * 16);
      gl_lds16(wb + (size_t)(o0 + row) * kC + k0 + cl * 8,
               (char*)sB + (p * 256 + wid * 64) * 16);
    }
    asm volatile("s_waitcnt vmcnt(0)" ::: "memory");
    __syncthreads();
#pragma unroll
    for (int kk = 0; kk < 2; ++kk) {
      s16x8 af[4], bfr[4];
      const int cl = kk * 4 + (lane >> 4);
#pragma unroll
      for (int i = 0; i < 4; ++i) {
        const int rA = wr * 64 + i * 16 + (lane & 15);
        af[i] = *(const s16x8*)((const char*)sA + rA * 128 + ((cl ^ (rA & 7)) << 4));
        const int rB = wc * 64 + i * 16 + (lane & 15);
        bfr[i] = *(const s16x8*)((const char*)sB + rB * 128 + ((cl ^ (rB & 7)) << 4));
      }
#pragma unroll
      for (int i = 0; i < 4; ++i)
#pragma unroll
        for (int j = 0; j < 4; ++j)
          acc[i][j] = __builtin_amdgcn_mfma_f32_16x16x32_bf16(asbf(af[i]), asbf(bfr[j]),
                                                              acc[i][j], 0, 0, 0);
    }
  }
  const int baseN = n0 + wr * 64 + ((lane >> 4) << 2);
#pragma unroll
  for (int j = 0; j < 4; ++j) {
    const int o = o0 + wc * 64 + j * 16 + (lane & 15);
    const float bs = bias[o];
#pragma unroll
    for (int i = 0; i < 4; ++i) {
      const int nb = baseN + i * 16;
      if (MODE == 0) {
        if (o < 1024) {
#pragma unroll
          for (int r = 0; r < 4; ++r)
            qkT[(rowb + nb + r) * (size_t)kO + o] = f2bf(acc[i][j][r] + bs);
        } else {
          unsigned short pk[4];
#pragma unroll
          for (int r = 0; r < 4; ++r) pk[r] = f2bf(acc[i][j][r] + bs);
          *(uint2*)(vbuf + ((size_t)b * 512 + (o - 1024)) * kN + nb) = *(uint2*)pk;
        }
      } else {
        const size_t oo = ((size_t)b * kC + o) * kN + nb;
        const f32x4 xv = *(const f32x4*)(xres + oo);
        f32x4 ov;
        ov[0] = acc[i][j][0] + bs + xv[0];
        ov[1] = acc[i][j][1] + bs + xv[1];
        ov[2] = acc[i][j][2] + bs + xv[2];
        ov[3] = acc[i][j][3] + bs + xv[3];
        *(f32x4*)(outp + oo) = ov;
      }
    }
  }
}

// ---------------- flash attention: block = (qtile of 128 rows, h, b) ----------------
__global__ __launch_bounds__(256, 2) void k_attn(const unsigned short* __restrict__ qkT,
                                                 const unsigned short* __restrict__ vbuf,
                                                 unsigned short* __restrict__ aoT) {
  int qt = blockIdx.x, h = blockIdx.y, b = blockIdx.z;
  int t = threadIdx.x, lane = t & 63, wid = t >> 6;
  __shared__ unsigned short sK[64 * 128];  // [m][d] swizzled
  __shared__ unsigned short sV[128 * 64];  // [d][m] swizzled
  __shared__ unsigned short sP[128 * 64];  // [n][m] swizzled (per-wave 32-row bands)
  const float scale = 0.08838834764831845f;  // 1/sqrt(128)
  const int qrow0 = qt * 128 + wid * 32;
  s16x8 qf[2][4];
#pragma unroll
  for (int bi = 0; bi < 2; ++bi)
#pragma unroll
    for (int kk = 0; kk < 4; ++kk)
      qf[bi][kk] = *(const s16x8*)(qkT + ((size_t)b * kN + qrow0 + bi * 16 + (lane & 15)) * kO +
                                   h * 128 + kk * 32 + ((lane >> 4) << 3));
  f32x4 oc[2][8];
  const f32x4 zf = {0.f, 0.f, 0.f, 0.f};
#pragma unroll
  for (int bi = 0; bi < 2; ++bi)
#pragma unroll
    for (int dj = 0; dj < 8; ++dj) oc[bi][dj] = zf;
  float mrun[8], lrun[8];
#pragma unroll
  for (int i = 0; i < 8; ++i) { mrun[i] = -__builtin_inff(); lrun[i] = 0.f; }
#pragma unroll 1
  for (int mt = 0; mt < 16; ++mt) {
    const int m0 = mt * 64;
    __syncthreads();
#pragma unroll
    for (int p = 0; p < 4; ++p) {
      const int id = p * 256 + t;
      {
        const int row = id >> 4, cp = id & 15, cl = cp ^ (row & 7);
        gl_lds16(qkT + ((size_t)b * kN + m0 + row) * kO + 512 + h * 128 + cl * 8,
                 (char*)sK + (p * 256 + wid * 64) * 16);
      }
      {
        const int row = id >> 3, cp = id & 7, cl = cp ^ (row & 7);
        gl_lds16(vbuf + ((size_t)b * 512 + h * 128 + row) * kN + m0 + cl * 8,
                 (char*)sV + (p * 256 + wid * 64) * 16);
      }
    }
    asm volatile("s_waitcnt vmcnt(0)" ::: "memory");
    __syncthreads();
    f32x4 sacc[2][4];
#pragma unroll
    for (int bi = 0; bi < 2; ++bi)
#pragma unroll
      for (int j = 0; j < 4; ++j) sacc[bi][j] = zf;
#pragma unroll
    for (int kk = 0; kk < 4; ++kk) {
      s16x8 kf[4];
      const int cl = kk * 4 + (lane >> 4);
#pragma unroll
      for (int j = 0; j < 4; ++j) {
        const int rm = j * 16 + (lane & 15);
        kf[j] = *(const s16x8*)((const char*)sK + rm * 256 + ((cl ^ (rm & 7)) << 4));
      }
#pragma unroll
      for (int bi = 0; bi < 2; ++bi)
#pragma unroll
        for (int j = 0; j < 4; ++j)
          sacc[bi][j] = __builtin_amdgcn_mfma_f32_16x16x32_bf16(asbf(qf[bi][kk]), asbf(kf[j]),
                                                                sacc[bi][j], 0, 0, 0);
    }
    // online softmax (row = (lane>>4)*4 + r within 16-row frag)
#pragma unroll
    for (int bi = 0; bi < 2; ++bi) {
#pragma unroll
      for (int r = 0; r < 4; ++r) {
        const int si = bi * 4 + r;
        float s0 = sacc[bi][0][r] * scale, s1 = sacc[bi][1][r] * scale;
        float s2 = sacc[bi][2][r] * scale, s3 = sacc[bi][3][r] * scale;
        float c = fmaxf(fmaxf(s0, s1), fmaxf(s2, s3));
        c = fmaxf(c, __shfl_xor(c, 1));
        c = fmaxf(c, __shfl_xor(c, 2));
        c = fmaxf(c, __shfl_xor(c, 4));
        c = fmaxf(c, __shfl_xor(c, 8));
        const float mnew = fmaxf(mrun[si], c);
        const float alpha = __expf(mrun[si] - mnew);
        mrun[si] = mnew;
        lrun[si] *= alpha;
#pragma unroll
        for (int dj = 0; dj < 8; ++dj) oc[bi][dj][r] *= alpha;
        const int nrow = wid * 32 + bi * 16 + ((lane >> 4) << 2) + r;
        float pv[4] = {__expf(s0 - mnew), __expf(s1 - mnew), __expf(s2 - mnew), __expf(s3 - mnew)};
        float rs = 0.f;
#pragma unroll
        for (int j = 0; j < 4; ++j) {
          rs += pv[j];
          const int m = j * 16 + (lane & 15);
          *(unsigned short*)((char*)sP + nrow * 128 + (((m >> 3) ^ (nrow & 7)) << 4) +
                             ((m & 7) << 1)) = f2bf(pv[j]);
        }
        rs += __shfl_xor(rs, 1);
        rs += __shfl_xor(rs, 2);
        rs += __shfl_xor(rs, 4);
        rs += __shfl_xor(rs, 8);
        lrun[si] += rs;
      }
    }
    // PV: O[n][d] += P[n][m] * V[d][m]
#pragma unroll
    for (int ks = 0; ks < 2; ++ks) {
      s16x8 pf[2], vf[8];
      const int cl = ks * 4 + (lane >> 4);
#pragma unroll
      for (int bi = 0; bi < 2; ++bi) {
        const int rp = wid * 32 + bi * 16 + (lane & 15);
        pf[bi] = *(const s16x8*)((const char*)sP + rp * 128 + ((cl ^ (rp & 7)) << 4));
      }
#pragma unroll
      for (int dj = 0; dj < 8; ++dj) {
        const int rv = dj * 16 + (lane & 15);
        vf[dj] = *(const s16x8*)((const char*)sV + rv * 128 + ((cl ^ (rv & 7)) << 4));
      }
#pragma unroll
      for (int bi = 0; bi < 2; ++bi)
#pragma unroll
        for (int dj = 0; dj < 8; ++dj)
          oc[bi][dj] = __builtin_amdgcn_mfma_f32_16x16x32_bf16(asbf(pf[bi]), asbf(vf[dj]),
                                                               oc[bi][dj], 0, 0, 0);
    }
  }
#pragma unroll
  for (int bi = 0; bi < 2; ++bi) {
#pragma unroll
    for (int r = 0; r < 4; ++r) {
      const float inv = 1.f / lrun[bi * 4 + r];
      const int n = qrow0 + bi * 16 + ((lane >> 4) << 2) + r;
#pragma unroll
      for (int dj = 0; dj < 8; ++dj) {
        const int d = dj * 16 + (lane & 15);
        aoT[((size_t)b * kN + n) * kC + h * 128 + d] = f2bf(oc[bi][dj][r] * inv);
      }
    }
  }
}

extern "C" void kernel_launch(void* const* d_in, const int* in_sizes, int n_in,
                              void* d_out, int out_size, void* d_ws, size_t ws_size,
                              hipStream_t stream) {
  const float* x = (const float*)d_in[0];
  const float* norm_w = (const float*)d_in[1];
  const float* norm_b = (const float*)d_in[2];
  const float* qkv_w = (const float*)d_in[3];
  const float* qkv_b = (const float*)d_in[4];
  const float* proj_w = (const float*)d_in[5];
  const float* proj_b = (const float*)d_in[6];
  float* out = (float*)d_out;
  char* ws = (char*)d_ws;
  const size_t OFF_MEAN = 0;
  const size_t OFF_RSTD = 2048;
  const size_t OFF_WQ = 4096;
  const size_t OFF_WP = OFF_WQ + (size_t)1536 * 512 * 2;
  const size_t OFF_XT = OFF_WP + (size_t)512 * 512 * 2;
  const size_t OFF_QKT = OFF_XT + (size_t)16 * 1024 * 512 * 2;
  const size_t OFF_V = OFF_QKT + (size_t)16 * 1024 * 1536 * 2;
  const size_t NEED = OFF_V + (size_t)16 * 512 * 1024 * 2;  // ~86 MB
  if (ws_size < NEED) return;
  float* meanp = (float*)(ws + OFF_MEAN);
  float* rstdp = (float*)(ws + OFF_RSTD);
  unsigned short* wq = (unsigned short*)(ws + OFF_WQ);
  unsigned short* wp = (unsigned short*)(ws + OFF_WP);
  unsigned short* xt = (unsigned short*)(ws + OFF_XT);
  unsigned short* qkT = (unsigned short*)(ws + OFF_QKT);
  unsigned short* vb = (unsigned short*)(ws + OFF_V);
  unsigned short* aoT = xt;  // xhat is dead after qkv GEMM; reuse for attn output

  k_wconv<<<768, 256, 0, stream>>>(qkv_w, wq, 1536 * 512 / 4);
  k_wconv<<<256, 256, 0, stream>>>(proj_w, wp, 512 * 512 / 4);
  k_gnstats<<<512, 256, 0, stream>>>(x, meanp, rstdp);
  k_gnapply<<<2048, 256, 0, stream>>>(x, norm_w, norm_b, meanp, rstdp, xt);
  k_gemm<0><<<dim3(96, 16), 256, 0, stream>>>(xt, wq, qkv_b, qkT, vb, nullptr, nullptr);
  k_attn<<<dim3(8, 4, 16), 256, 0, stream>>>(qkT, vb, aoT);
  k_gemm<1><<<dim3(32, 16), 256, 0, stream>>>(aoT, wp, proj_b, nullptr, nullptr, x, out);
}

// Round 2
// 154.126 us; speedup vs baseline: 1.0996x; 1.0996x over previous
//
#include <hip/hip_runtime.h>
#include <stdint.h>

#define DEV __device__ __forceinline__

typedef __attribute__((ext_vector_type(4))) float f32x4;
typedef __attribute__((ext_vector_type(8))) short s16x8;
typedef __attribute__((ext_vector_type(8))) __bf16 bf16x8;

constexpr int kB = 16, kC = 512, kN = 1024;
constexpr int kO = 1536;
constexpr int kG = 32, kCPG = 16;
constexpr float kEps = 1e-5f;

DEV unsigned short f2bf(float f) {
  union { float f; uint32_t u; } cv; cv.f = f;
  uint32_t u = cv.u;
  return (unsigned short)((u + 0x7FFFu + ((u >> 16) & 1u)) >> 16);
}

DEV bf16x8 asbf(s16x8 v) { return __builtin_bit_cast(bf16x8, v); }

DEV void gl_lds16(const void* g, void* l) {
  __builtin_amdgcn_global_load_lds(
      (const __attribute__((address_space(1))) uint32_t*)g,
      (__attribute__((address_space(3))) uint32_t*)l, 16, 0, 0);
}

// ---------------- weight fp32 -> bf16 ----------------
__global__ __launch_bounds__(256) void k_wconv(const float* __restrict__ src,
                                               unsigned short* __restrict__ dst, int n4) {
  int i = blockIdx.x * 256 + threadIdx.x;
  if (i >= n4) return;
  f32x4 v = ((const f32x4*)src)[i];
  unsigned short o[4];
  o[0] = f2bf(v[0]); o[1] = f2bf(v[1]); o[2] = f2bf(v[2]); o[3] = f2bf(v[3]);
  ((uint2*)dst)[i] = *(uint2*)o;
}

// ---------------- GroupNorm stats: one block per (b,g) ----------------
__global__ __launch_bounds__(256) void k_gnstats(const float* __restrict__ x,
                                                 float* __restrict__ meanp,
                                                 float* __restrict__ rstdp) {
  int bg = blockIdx.x;  // 0..511
  const f32x4* p4 = (const f32x4*)(x + (size_t)bg * (kCPG * kN));
  float s = 0.f, s2 = 0.f;
  for (int i = threadIdx.x; i < (kCPG * kN / 4); i += 256) {
    f32x4 v = p4[i];
    s += v[0] + v[1] + v[2] + v[3];
    s2 += v[0] * v[0] + v[1] * v[1] + v[2] * v[2] + v[3] * v[3];
  }
#pragma unroll
  for (int m = 32; m >= 1; m >>= 1) { s += __shfl_xor(s, m); s2 += __shfl_xor(s2, m); }
  __shared__ float rb[8];
  int lane = threadIdx.x & 63, wid = threadIdx.x >> 6;
  if (lane == 0) { rb[wid * 2] = s; rb[wid * 2 + 1] = s2; }
  __syncthreads();
  if (threadIdx.x == 0) {
    float S = rb[0] + rb[2] + rb[4] + rb[6];
    float S2 = rb[1] + rb[3] + rb[5] + rb[7];
    float mu = S * (1.f / 16384.f);
    float var = S2 * (1.f / 16384.f) - mu * mu;
    meanp[bg] = mu;
    rstdp[bg] = rsqrtf(var + kEps);
  }
}

// ---------------- GN apply + transpose to token-major bf16 ----------------
__global__ __launch_bounds__(256) void k_gnapply(const float* __restrict__ x,
                                                 const float* __restrict__ gw,
                                                 const float* __restrict__ gb,
                                                 const float* __restrict__ meanp,
                                                 const float* __restrict__ rstdp,
                                                 unsigned short* __restrict__ xt) {
  int bid = blockIdx.x;
  int b = bid >> 7;
  int ct = (bid >> 4) & 7;
  int nt = bid & 15;
  int c0 = ct * 64, n0 = nt * 64;
  __shared__ float tile[64][65];
  int t = threadIdx.x;
#pragma unroll
  for (int pass = 0; pass < 4; ++pass) {
    int r = pass * 16 + (t >> 4);
    int col = (t & 15) << 2;
    int c = c0 + r;
    f32x4 v = *(const f32x4*)(x + ((size_t)b * kC + c) * kN + n0 + col);
    int g = b * kG + (c >> 4);
    float rs = rstdp[g];
    float a = rs * gw[c];
    float bb = gb[c] - meanp[g] * a;
    tile[r][col + 0] = v[0] * a + bb;
    tile[r][col + 1] = v[1] * a + bb;
    tile[r][col + 2] = v[2] * a + bb;
    tile[r][col + 3] = v[3] * a + bb;
  }
  __syncthreads();
#pragma unroll
  for (int pass = 0; pass < 2; ++pass) {
    int nr = pass * 32 + (t >> 3);
    int cb = (t & 7) << 3;
    unsigned short o[8];
#pragma unroll
    for (int j = 0; j < 8; ++j) o[j] = f2bf(tile[cb + j][nr]);
    *(uint4*)(xt + ((size_t)b * kN + n0 + nr) * kC + c0 + cb) = *(uint4*)o;
  }
}

// ---------------- GEMM: D[n][o] = sum_c act[b][n][c] * W[o][c]  ----------------
template <int MODE>
__global__ __launch_bounds__(256) void k_gemm(const unsigned short* __restrict__ act,
                                              const unsigned short* __restrict__ wb,
                                              const float* __restrict__ bias,
                                              unsigned short* __restrict__ qkT,
                                              unsigned short* __restrict__ vbuf,
                                              const float* __restrict__ xres,
                                              float* __restrict__ outp) {
  int b = blockIdx.y;
  int nt = blockIdx.x & 7, ot = blockIdx.x >> 3;
  int n0 = nt << 7, o0 = ot << 7;
  int t = threadIdx.x, lane = t & 63, wid = t >> 6;
  int wr = wid >> 1, wc = wid & 1;
  __shared__ unsigned short sA[128 * 64];
  __shared__ unsigned short sB[128 * 64];
  f32x4 acc[4][4];
  const f32x4 zf = {0.f, 0.f, 0.f, 0.f};
#pragma unroll
  for (int i = 0; i < 4; ++i)
#pragma unroll
    for (int j = 0; j < 4; ++j) acc[i][j] = zf;
  const size_t rowb = (size_t)b * kN;
#pragma unroll 1
  for (int kt = 0; kt < 8; ++kt) {
    const int k0 = kt << 6;
    __syncthreads();
#pragma unroll
    for (int p = 0; p < 4; ++p) {
      const int id = p * 256 + t;
      const int row = id >> 3, cp = id & 7;
      const int cl = cp ^ (row & 7);  // source chunk pre-swizzle (involution)
      gl_lds16(act + (rowb + n0 + row) * (size_t)kC + k0 + cl * 8,
               (char*)sA + (p * 256 + wid * 64) * 16);
      gl_lds16(wb + (size_t)(o0 + row) * kC + k0 + cl * 8,
               (char*)sB + (p * 256 + wid * 64) * 16);
    }
    asm volatile("s_waitcnt vmcnt(0)" ::: "memory");
    __syncthreads();
#pragma unroll
    for (int kk = 0; kk < 2; ++kk) {
      s16x8 af[4], bfr[4];
      const int cl = kk * 4 + (lane >> 4);
#pragma unroll
      for (int i = 0; i < 4; ++i) {
        const int rA = wr * 64 + i * 16 + (lane & 15);
        af[i] = *(const s16x8*)((const char*)sA + rA * 128 + ((cl ^ (rA & 7)) << 4));
        const int rB = wc * 64 + i * 16 + (lane & 15);
        bfr[i] = *(const s16x8*)((const char*)sB + rB * 128 + ((cl ^ (rB & 7)) << 4));
      }
#pragma unroll
      for (int i = 0; i < 4; ++i)
#pragma unroll
        for (int j = 0; j < 4; ++j)
          acc[i][j] = __builtin_amdgcn_mfma_f32_16x16x32_bf16(asbf(af[i]), asbf(bfr[j]),
                                                              acc[i][j], 0, 0, 0);
    }
  }
  const int baseN = n0 + wr * 64 + ((lane >> 4) << 2);
#pragma unroll
  for (int j = 0; j < 4; ++j) {
    const int o = o0 + wc * 64 + j * 16 + (lane & 15);
    const float bs = bias[o];
#pragma unroll
    for (int i = 0; i < 4; ++i) {
      const int nb = baseN + i * 16;
      if (MODE == 0) {
        if (o < 1024) {
#pragma unroll
          for (int r = 0; r < 4; ++r)
            qkT[(rowb + nb + r) * (size_t)kO + o] = f2bf(acc[i][j][r] + bs);
        } else {
          unsigned short pk[4];
#pragma unroll
          for (int r = 0; r < 4; ++r) pk[r] = f2bf(acc[i][j][r] + bs);
          *(uint2*)(vbuf + ((size_t)b * 512 + (o - 1024)) * kN + nb) = *(uint2*)pk;
        }
      } else {
        const size_t oo = ((size_t)b * kC + o) * kN + nb;
        const f32x4 xv = *(const f32x4*)(xres + oo);
        f32x4 ov;
        ov[0] = acc[i][j][0] + bs + xv[0];
        ov[1] = acc[i][j][1] + bs + xv[1];
        ov[2] = acc[i][j][2] + bs + xv[2];
        ov[3] = acc[i][j][3] + bs + xv[3];
        *(f32x4*)(outp + oo) = ov;
      }
    }
  }
}

// ---------------- flash attention v2: double-buffered K/V, phased softmax ----------------
// grid: (bh=64, qt=8) so the 8 q-tiles sharing one (b,h)'s K/V land on one XCD's L2.
__global__ __launch_bounds__(256, 2) void k_attn(const unsigned short* __restrict__ qkT,
                                                 const unsigned short* __restrict__ vbuf,
                                                 unsigned short* __restrict__ aoT) {
  const int bh = blockIdx.x, qt = blockIdx.y;
  const int b = bh >> 2, h = bh & 3;
  const int t = threadIdx.x, lane = t & 63, wid = t >> 6;
  __shared__ unsigned short sK[2][64 * 128];  // [m][d] swizzled, double-buffered
  __shared__ unsigned short sV[2][128 * 64];  // [d][m] swizzled, double-buffered
  __shared__ unsigned short sP[128 * 64];     // [n][m] swizzled (per-wave 32-row bands)
  const float kS2 = 0.08838834764831845f * 1.44269504088896f;  // 1/sqrt(128) * log2(e)
  const int qrow0 = qt * 128 + wid * 32;
  s16x8 qf[2][4];
#pragma unroll
  for (int bi = 0; bi < 2; ++bi)
#pragma unroll
    for (int kk = 0; kk < 4; ++kk)
      qf[bi][kk] = *(const s16x8*)(qkT + ((size_t)b * kN + qrow0 + bi * 16 + (lane & 15)) * kO +
                                   h * 128 + kk * 32 + ((lane >> 4) << 3));
  f32x4 oc[2][8];
  const f32x4 zf = {0.f, 0.f, 0.f, 0.f};
#pragma unroll
  for (int bi = 0; bi < 2; ++bi)
#pragma unroll
    for (int dj = 0; dj < 8; ++dj) oc[bi][dj] = zf;
  float mrun[8], lpart[8];
#pragma unroll
  for (int i = 0; i < 8; ++i) { mrun[i] = -__builtin_inff(); lpart[i] = 0.f; }

  auto stage = [&](int buf, int m0) {
#pragma unroll
    for (int p = 0; p < 4; ++p) {
      const int id = p * 256 + t;
      {
        const int row = id >> 4, cp = id & 15, cl = cp ^ (row & 7);
        gl_lds16(qkT + ((size_t)b * kN + m0 + row) * kO + 512 + h * 128 + cl * 8,
                 (char*)sK[buf] + (p * 256 + wid * 64) * 16);
      }
      {
        const int row = id >> 3, cp = id & 7, cl = cp ^ (row & 7);
        gl_lds16(vbuf + ((size_t)b * 512 + h * 128 + row) * kN + m0 + cl * 8,
                 (char*)sV[buf] + (p * 256 + wid * 64) * 16);
      }
    }
  };

  stage(0, 0);
#pragma unroll 1
  for (int mt = 0; mt < 16; ++mt) {
    const int cur = mt & 1;
    asm volatile("s_waitcnt vmcnt(0)" ::: "memory");  // buf[cur] staged (issued last iter)
    __syncthreads();  // all waves' stages landed; all reads of buf[cur^1] (prev tile) done
    if (mt < 15) stage(cur ^ 1, (mt + 1) * 64);  // prefetch: in flight across whole compute
    // ---- QK^T ----
    f32x4 sacc[2][4];
#pragma unroll
    for (int bi = 0; bi < 2; ++bi)
#pragma unroll
      for (int j = 0; j < 4; ++j) sacc[bi][j] = zf;
    __builtin_amdgcn_s_setprio(1);
#pragma unroll
    for (int kk = 0; kk < 4; ++kk) {
      s16x8 kf[4];
      const int cl = kk * 4 + (lane >> 4);
#pragma unroll
      for (int j = 0; j < 4; ++j) {
        const int rm = j * 16 + (lane & 15);
        kf[j] = *(const s16x8*)((const char*)sK[cur] + rm * 256 + ((cl ^ (rm & 7)) << 4));
      }
#pragma unroll
      for (int bi = 0; bi < 2; ++bi)
#pragma unroll
        for (int j = 0; j < 4; ++j)
          sacc[bi][j] = __builtin_amdgcn_mfma_f32_16x16x32_bf16(asbf(qf[bi][kk]), asbf(kf[j]),
                                                                sacc[bi][j], 0, 0, 0);
    }
    __builtin_amdgcn_s_setprio(0);
    // ---- softmax, phased for ILP ----
    // phase A: per-lane max over the 4 col-frags (raw scores; scale folded later)
    float cmax[8];
#pragma unroll
    for (int bi = 0; bi < 2; ++bi)
#pragma unroll
      for (int r = 0; r < 4; ++r)
        cmax[bi * 4 + r] = fmaxf(fmaxf(sacc[bi][0][r], sacc[bi][1][r]),
                                 fmaxf(sacc[bi][2][r], sacc[bi][3][r]));
    // phase B: 8 independent shfl-reduce chains, interleaved
#pragma unroll
    for (int st = 1; st <= 8; st <<= 1)
#pragma unroll
      for (int si = 0; si < 8; ++si) cmax[si] = fmaxf(cmax[si], __shfl_xor(cmax[si], st));
    // phase C: defer-max — only rescale when some row's max grew past THR (log2 domain)
    float cs[8];
    bool anyg = false;
#pragma unroll
    for (int si = 0; si < 8; ++si) {
      cs[si] = cmax[si] * kS2;
      anyg = anyg || (cs[si] > mrun[si] + 8.f);
    }
    if (__any(anyg)) {
#pragma unroll
      for (int bi = 0; bi < 2; ++bi)
#pragma unroll
        for (int r = 0; r < 4; ++r) {
          const int si = bi * 4 + r;
          const float mnew = fmaxf(mrun[si], cs[si]);
          const float alpha = exp2f(mrun[si] - mnew);
          mrun[si] = mnew;
          lpart[si] *= alpha;
#pragma unroll
          for (int dj = 0; dj < 8; ++dj) oc[bi][dj][r] *= alpha;
        }
    }
    // phase D: exp2 + P->LDS + per-lane partial row-sum (reduced once at the end)
#pragma unroll
    for (int bi = 0; bi < 2; ++bi)
#pragma unroll
      for (int r = 0; r < 4; ++r) {
        const int si = bi * 4 + r;
        const int nrow = wid * 32 + bi * 16 + ((lane >> 4) << 2) + r;
        const float mm = mrun[si];
        float pvs = 0.f;
#pragma unroll
        for (int j = 0; j < 4; ++j) {
          const float p = exp2f(sacc[bi][j][r] * kS2 - mm);
          pvs += p;
          const int m = j * 16 + (lane & 15);
          *(unsigned short*)((char*)sP + nrow * 128 + (((m >> 3) ^ (nrow & 7)) << 4) +
                             ((m & 7) << 1)) = f2bf(p);
        }
        lpart[si] += pvs;
      }
    // ---- PV: O[n][d] += P[n][m] * V[d][m] ----
    __builtin_amdgcn_s_setprio(1);
#pragma unroll
    for (int ks = 0; ks < 2; ++ks) {
      s16x8 pf[2], vf[8];
      const int cl = ks * 4 + (lane >> 4);
#pragma unroll
      for (int bi = 0; bi < 2; ++bi) {
        const int rp = wid * 32 + bi * 16 + (lane & 15);
        pf[bi] = *(const s16x8*)((const char*)sP + rp * 128 + ((cl ^ (rp & 7)) << 4));
      }
#pragma unroll
      for (int dj = 0; dj < 8; ++dj) {
        const int rv = dj * 16 + (lane & 15);
        vf[dj] = *(const s16x8*)((const char*)sV[cur] + rv * 128 + ((cl ^ (rv & 7)) << 4));
      }
#pragma unroll
      for (int bi = 0; bi < 2; ++bi)
#pragma unroll
        for (int dj = 0; dj < 8; ++dj)
          oc[bi][dj] = __builtin_amdgcn_mfma_f32_16x16x32_bf16(asbf(pf[bi]), asbf(vf[dj]),
                                                               oc[bi][dj], 0, 0, 0);
    }
    __builtin_amdgcn_s_setprio(0);
  }
#pragma unroll
  for (int bi = 0; bi < 2; ++bi) {
#pragma unroll
    for (int r = 0; r < 4; ++r) {
      float ls = lpart[bi * 4 + r];
#pragma unroll
      for (int st = 1; st <= 8; st <<= 1) ls += __shfl_xor(ls, st);
      const float inv = 1.f / ls;
      const int n = qrow0 + bi * 16 + ((lane >> 4) << 2) + r;
#pragma unroll
      for (int dj = 0; dj < 8; ++dj) {
        const int d = dj * 16 + (lane & 15);
        aoT[((size_t)b * kN + n) * kC + h * 128 + d] = f2bf(oc[bi][dj][r] * inv);
      }
    }
  }
}

extern "C" void kernel_launch(void* const* d_in, const int* in_sizes, int n_in,
                              void* d_out, int out_size, void* d_ws, size_t ws_size,
                              hipStream_t stream) {
  const float* x = (const float*)d_in[0];
  const float* norm_w = (const float*)d_in[1];
  const float* norm_b = (const float*)d_in[2];
  const float* qkv_w = (const float*)d_in[3];
  const float* qkv_b = (const float*)d_in[4];
  const float* proj_w = (const float*)d_in[5];
  const float* proj_b = (const float*)d_in[6];
  float* out = (float*)d_out;
  char* ws = (char*)d_ws;
  const size_t OFF_MEAN = 0;
  const size_t OFF_RSTD = 2048;
  const size_t OFF_WQ = 4096;
  const size_t OFF_WP = OFF_WQ + (size_t)1536 * 512 * 2;
  const size_t OFF_XT = OFF_WP + (size_t)512 * 512 * 2;
  const size_t OFF_QKT = OFF_XT + (size_t)16 * 1024 * 512 * 2;
  const size_t OFF_V = OFF_QKT + (size_t)16 * 1024 * 1536 * 2;
  const size_t NEED = OFF_V + (size_t)16 * 512 * 1024 * 2;  // ~86 MB
  if (ws_size < NEED) return;
  float* meanp = (float*)(ws + OFF_MEAN);
  float* rstdp = (float*)(ws + OFF_RSTD);
  unsigned short* wq = (unsigned short*)(ws + OFF_WQ);
  unsigned short* wp = (unsigned short*)(ws + OFF_WP);
  unsigned short* xt = (unsigned short*)(ws + OFF_XT);
  unsigned short* qkT = (unsigned short*)(ws + OFF_QKT);
  unsigned short* vb = (unsigned short*)(ws + OFF_V);
  unsigned short* aoT = xt;  // xhat is dead after qkv GEMM; reuse for attn output

  k_wconv<<<768, 256, 0, stream>>>(qkv_w, wq, 1536 * 512 / 4);
  k_wconv<<<256, 256, 0, stream>>>(proj_w, wp, 512 * 512 / 4);
  k_gnstats<<<512, 256, 0, stream>>>(x, meanp, rstdp);
  k_gnapply<<<2048, 256, 0, stream>>>(x, norm_w, norm_b, meanp, rstdp, xt);
  k_gemm<0><<<dim3(96, 16), 256, 0, stream>>>(xt, wq, qkv_b, qkT, vb, nullptr, nullptr);
  k_attn<<<dim3(64, 8), 256, 0, stream>>>(qkT, vb, aoT);
  k_gemm<1><<<dim3(32, 16), 256, 0, stream>>>(aoT, wp, proj_b, nullptr, nullptr, x, out);
}